// Round 2
// baseline (109.084 us; speedup 1.0000x reference)
//
#include <hip/hip_runtime.h>
#include <math.h>

// B=2, HD=4, H=W=128, KSIZE=7 (K=49), NSP=9, S=64
#define BN   2
#define HDN  4
#define HN   128
#define WN   128
#define KS   7
#define KK   49
#define NSPN 9
#define SN   64
#define PPB  32      // pixels per block
#define TPB  256     // 4 waves: (pixHalf 0/1) x (spHalf 0/1)
#define PROW 52      // padded LDS row stride (floats), 16B-aligned

// v4: sp-split x2 + wave autonomy. Each wave owns 16 pixels x 4 heads and
// HALF the sp planes, gathering into a wave-private double-buffered LDS
// region -> no inner __syncthreads (intra-wave vmcnt/lgkmcnt only), waves
// slip freely. 2x resident waves (4096 vs 2048), serial phase chain halved
// (9 -> 4/5). Partial acc[49] pairs combine once at the end via LDS (pbuf
// region reused). Softmax duplicated per pair (VALU is ~9% busy - free).
__global__ __launch_bounds__(TPB, 2) void attn_rw4(
    const float* __restrict__ attn,
    const float* __restrict__ sims,
    const int*   __restrict__ sinds,
    float*       __restrict__ out)
{
    // pbuf during the loop (4 waves x 2 bufs x 16 rows x PROW), xbuf at the end
    __shared__ __align__(16) float smem[4 * 2 * 16 * PROW];   // 6656 floats = 26.6 KB
    __shared__ int   g_lds[PPB * NSPN];
    __shared__ float pi_lds[PPB * NSPN];

    const int t    = threadIdx.x;
    const int lane = t & 63;
    const int w    = t >> 6;                 // wave id 0..3
    const int pixHalf = w & 1;               // which 16 pixels
    const int sph  = w >> 1;                 // which sp half
    const int bx   = blockIdx.x;
    const int wseg = bx & 3;
    const int hh   = (bx >> 2) & 127;
    const int b    = bx >> 9;
    const int ww0  = wseg * PPB;

    const int pixL  = lane >> 2;             // 0..15 within wave
    const int hd    = lane & 3;
    const int pix_c = pixHalf * 16 + pixL;   // 0..31 within block

    const float* simsB = sims + ((size_t)b << 20);   // b * 64*128*128
    int hs = hh - 3; hs = max(0, min(HN - KS, hs));  // uniform per block

    // ---- batched attn loads (dwordx4, dword-aligned ok) ----
    float a[KK];
    const size_t abase =
        ((((size_t)b * HDN + hd) * HN + hh) * WN + (ww0 + pix_c)) * (size_t)KK;
    {
        const float* ap = attn + abase;
        #pragma unroll
        for (int j = 0; j < 12; ++j)
            __builtin_memcpy(&a[4 * j], ap + 4 * j, 16);
        a[48] = ap[48];
    }

    // ---- reg-staged sinds + pi: loads first, LDS writes late ----
    const int sbase = ((b * HN + hh) * WN + ww0) * NSPN;
    {
        int s0 = sinds[sbase + t];
        int s1 = (t < 32) ? sinds[sbase + 256 + t] : 0;
        g_lds[t] = s0;
        if (t < 32) g_lds[256 + t] = s1;
        float pv0 = simsB[(s0 << 14) + hh * WN + ww0 + (t / NSPN)];
        float pv1 = (t < 32) ? simsB[(s1 << 14) + hh * WN + ww0 + ((t + 256) / NSPN)] : 0.0f;
        pi_lds[t] = pv0;
        if (t < 32) pi_lds[256 + t] = pv1;
    }
    __syncthreads();                         // g_lds / pi_lds published (only barrier before epilogue)

    // gather lane constants
    const int  gki  = lane / KS;
    const int  gkj  = lane - gki * KS;
    const bool gact = lane < KK;
    const int  laneoff = gact ? (gki * WN + gkj) : 0;   // clamped: inactive lanes stay in-bounds

    float* pb = &smem[w * (2 * 16 * PROW)];  // wave-private region
    float gr[16];

    auto gather_load = [&](int sp) {
        int gv = 0;
        if (lane < 16)
            gv = g_lds[(pixHalf * 16 + lane) * NSPN + sp];
        #pragma unroll
        for (int i = 0; i < 16; ++i) {
            int g    = __builtin_amdgcn_readlane(gv, i);   // scalar g per pixel
            int pixg = ww0 + pixHalf * 16 + i;
            int ws   = pixg - 3; ws = max(0, min(WN - KS, ws));
            gr[i] = simsB[(g << 14) + hs * WN + ws + laneoff];
        }
    };
    auto gather_store = [&](int buf) {
        if (gact) {
            #pragma unroll
            for (int i = 0; i < 16; ++i)
                pb[(buf * 16 + i) * PROW + lane] = gr[i];
        }
    };

    // sph0: sp 0..3 (epilogue wave does less); sph1: sp 4..8
    const int spStart = sph ? 4 : 0;
    const int spCnt   = sph ? 5 : 4;

    gather_load(spStart);                    // 16 loads in flight

    // softmax overlaps first gather's latency (pure VALU)
    {
        float m0 = a[0], m1 = a[1], m2 = a[2], m3 = a[3];
        #pragma unroll
        for (int k = 4; k < KK; k += 4) {
            m0 = fmaxf(m0, a[k]);
            if (k + 1 < KK) m1 = fmaxf(m1, a[k + 1]);
            if (k + 2 < KK) m2 = fmaxf(m2, a[k + 2]);
            if (k + 3 < KK) m3 = fmaxf(m3, a[k + 3]);
        }
        float m = fmaxf(fmaxf(m0, m1), fmaxf(m2, m3));
        #pragma unroll
        for (int k = 0; k < KK; ++k) a[k] = __expf(a[k] - m);
    }

    gather_store(0);                         // intra-wave vmcnt only

    float acc[KK];
    #pragma unroll
    for (int k = 0; k < KK; ++k) acc[k] = 0.0f;

    for (int s = 0; s < spCnt; ++s) {
        const int buf = s & 1;
        if (s + 1 < spCnt) gather_load(spStart + s + 1);   // next plane in flight

        // load p row into regs (12 x b128 + 1); 4 lanes/row -> broadcast-friendly
        float p[KK];
        const float* prow = pb + (buf * 16 + pixL) * PROW;
        #pragma unroll
        for (int k4 = 0; k4 < 12; ++k4) {
            float4 v = *(const float4*)(prow + k4 * 4);
            p[k4 * 4 + 0] = v.x; p[k4 * 4 + 1] = v.y;
            p[k4 * 4 + 2] = v.z; p[k4 * 4 + 3] = v.w;
        }
        p[48] = prow[48];

        // denom: 4-way split FMA chains
        float d0 = 0.f, d1 = 0.f, d2 = 0.f, d3 = 0.f;
        #pragma unroll
        for (int k = 0; k < 48; k += 4) {
            d0 = fmaf(a[k + 0], p[k + 0], d0);
            d1 = fmaf(a[k + 1], p[k + 1], d1);
            d2 = fmaf(a[k + 2], p[k + 2], d2);
            d3 = fmaf(a[k + 3], p[k + 3], d3);
        }
        d0 = fmaf(a[48], p[48], d0);
        float d = (d0 + d1) + (d2 + d3);

        float pi   = pi_lds[pix_c * NSPN + spStart + s];
        float coef = pi * __builtin_amdgcn_rcpf(d + 1e-10f);

        #pragma unroll
        for (int k = 0; k < KK; ++k) acc[k] = fmaf(coef, p[k], acc[k]);

        if (s + 1 < spCnt) gather_store(buf ^ 1);   // intra-wave; no barrier
    }

    // ---- combine sp-halves: sph1 publishes acc via LDS (pbuf reused) ----
    __syncthreads();                         // all waves done with pbuf
    if (sph) {
        float* xr = &smem[(t & 127) * PROW];
        #pragma unroll
        for (int k4 = 0; k4 < 12; ++k4) {
            float4 v = make_float4(acc[4 * k4], acc[4 * k4 + 1],
                                   acc[4 * k4 + 2], acc[4 * k4 + 3]);
            *(float4*)(xr + 4 * k4) = v;
        }
        xr[48] = acc[48];
    }
    __syncthreads();
    if (!sph) {
        const float* xr = &smem[t * PROW];   // partner = t + 128, same (pix,hd)
        #pragma unroll
        for (int k4 = 0; k4 < 12; ++k4) {
            float4 v = *(const float4*)(xr + 4 * k4);
            acc[4 * k4 + 0] += v.x; acc[4 * k4 + 1] += v.y;
            acc[4 * k4 + 2] += v.z; acc[4 * k4 + 3] += v.w;
        }
        acc[48] += xr[48];

        #pragma unroll
        for (int k = 0; k < KK; ++k) a[k] *= acc[k];
        float* op = out + abase;
        #pragma unroll
        for (int j = 0; j < 12; ++j)
            __builtin_memcpy(op + 4 * j, &a[4 * j], 16);   // dwordx4 stores
        op[48] = a[48];
    }
}

extern "C" void kernel_launch(void* const* d_in, const int* in_sizes, int n_in,
                              void* d_out, int out_size, void* d_ws, size_t ws_size,
                              hipStream_t stream) {
    const float* attn  = (const float*)d_in[0];
    const float* sims  = (const float*)d_in[1];
    const int*   sinds = (const int*)d_in[2];
    float*       outp  = (float*)d_out;

    // blocks: b(2) x hh(128) x wseg(4) = 1024, 4 waves each
    const int blocks = BN * HN * (WN / PPB);
    attn_rw4<<<blocks, TPB, 0, stream>>>(attn, sims, sinds, outp);
}